// Round 10
// baseline (531.496 us; speedup 1.0000x reference)
//
#include <hip/hip_runtime.h>
#include <stdint.h>

#define NN 100000      // nodes
#define NE 1600000     // edges
#define MAXDEG 64      // Poisson(16): P(deg>64) ~ 1e-19, safe cap
#define NSLICE 8       // XCD count; slice = blockIdx & 7 (perf heuristic only)
#define SLICE_SZ 12500 // nodes per slice
#define CHUNK 6400     // edges per block; NE/CHUNK = 250 chunks per slice

typedef __attribute__((ext_vector_type(8))) short short8;
typedef __attribute__((ext_vector_type(4))) float f32x4;
typedef __attribute__((ext_vector_type(4))) int i32x4;

__device__ __forceinline__ float bflo(unsigned v) { return __uint_as_float(v << 16); }
__device__ __forceinline__ float bfhi(unsigned v) { return __uint_as_float(v & 0xffff0000u); }
__device__ __forceinline__ unsigned short f2bf(float f) {   // round-to-nearest-even
  unsigned u = __float_as_uint(f);
  u += 0x7fff + ((u >> 16) & 1);
  return (unsigned short)(u >> 16);
}

// ---- XCD-sliced bucket build; NT edge reads keep the stream out of L2 so the
// 3.2MB bucket slice stays resident (writes merge instead of re-dirtying).
__global__ __launch_bounds__(256) void build_buckets(const int* __restrict__ src,
                                                     const int* __restrict__ dst,
                                                     int* __restrict__ cnt,
                                                     int* __restrict__ buck) {
  const int slice = blockIdx.x & (NSLICE - 1);
  const int chunk = blockIdx.x >> 3;
  const int c0 = chunk * CHUNK;
  const int lo = slice * SLICE_SZ, hi = lo + SLICE_SZ;
  for (int e = c0 + (int)threadIdx.x * 4; e < c0 + CHUNK; e += 1024) {
    i32x4 d = __builtin_nontemporal_load((const i32x4*)(dst + e));
    i32x4 s = __builtin_nontemporal_load((const i32x4*)(src + e));
    if (d[0] >= lo && d[0] < hi) { int p = atomicAdd(&cnt[d[0]], 1); if (p < MAXDEG) buck[d[0] * MAXDEG + p] = s[0]; }
    if (d[1] >= lo && d[1] < hi) { int p = atomicAdd(&cnt[d[1]], 1); if (p < MAXDEG) buck[d[1] * MAXDEG + p] = s[1]; }
    if (d[2] >= lo && d[2] < hi) { int p = atomicAdd(&cnt[d[2]], 1); if (p < MAXDEG) buck[d[2] * MAXDEG + p] = s[2]; }
    if (d[3] >= lo && d[3] < hi) { int p = atomicAdd(&cnt[d[3]], 1); if (p < MAXDEG) buck[d[3] * MAXDEG + p] = s[3]; }
  }
}

// ---- f32 -> packed bf16x2 (float4 per thread) ----
__global__ __launch_bounds__(256) void to_bf16(const float* __restrict__ x,
                                               unsigned* __restrict__ xb) {
  int i = blockIdx.x * 256 + threadIdx.x;     // over NN*32
  if (i >= NN * 32) return;
  float4 v = ((const float4*)x)[i];
  uint2 o;
  o.x = ((unsigned)f2bf(v.y) << 16) | f2bf(v.x);
  o.y = ((unsigned)f2bf(v.w) << 16) | f2bf(v.z);
  ((uint2*)xb)[i] = o;
}

// ---- one-time W transpose -> k-major bf16: WT[m][k], k = [Wl rows | Wr rows] ----
__global__ __launch_bounds__(256) void transpose_w(const float* __restrict__ W1l,
                                                   const float* __restrict__ W1r,
                                                   const float* __restrict__ W2l,
                                                   const float* __restrict__ W2r,
                                                   unsigned short* __restrict__ WT1,
                                                   unsigned short* __restrict__ WT2) {
  int t = blockIdx.x * 256 + threadIdx.x;
  if (t < 128 * 256) {
    int m = t >> 8, k = t & 255;
    float v = (k < 128) ? W1l[k * 128 + m] : W1r[(k - 128) * 128 + m];
    WT1[t] = f2bf(v);
  } else {
    int i = t - 128 * 256;
    if (i < 64 * 256) {
      int m = i >> 8, k = i & 255;
      float v = (k < 128) ? W2l[k * 64 + m] : W2r[(k - 128) * 64 + m];
      WT2[i] = f2bf(v);
    }
  }
}

// ---- FUSED layer: gather-mean into wave-private LDS rows, then MFMA.
// Barrier-free (wave wv owns rows [wv*16,wv*16+16)). Gather uses
// v_readlane (SGPR slot -> SGPR-base loads, no ds_bpermute) and processes
// rows in PAIRS so 32 loads are in flight per wave.
template <int M, bool RELU, typename OutT>
__global__ __launch_bounds__(256) void sage_fused(const unsigned* __restrict__ xb,
                                                  const int* __restrict__ cnt,
                                                  const int* __restrict__ buck,
                                                  const unsigned short* __restrict__ WT,
                                                  const float* __restrict__ bias,
                                                  OutT* __restrict__ out) {
  constexpr int LDA = 264;                       // +8 bf16 pad; 528B pitch
  __shared__ unsigned short sA[64][LDA];

  const int t = threadIdx.x;
  const int lane = t & 63;
  const int wv = t >> 6;
  const int node0 = blockIdx.x * 64;
  const int nb = node0 + wv * 16;                // this wave's 16 nodes

  // ---- prefetch: 16 bucket rows (per-lane) + 16 x rows + uniform degrees ----
  int slot[16]; unsigned xr[16]; int degU[16];
#pragma unroll
  for (int i = 0; i < 16; i++) {
    int node = nb + i;                           // wave-uniform
    if (node < NN) {
      slot[i] = buck[(size_t)node * MAXDEG + lane];
      xr[i]   = xb[(size_t)node * 64 + lane];
      degU[i] = __builtin_amdgcn_readfirstlane(cnt[node]);
    } else { slot[i] = 0; xr[i] = 0u; degU[i] = 0; }
  }

  // ---- gather-mean, two rows at a time (32 loads in flight) ----
#pragma unroll
  for (int i = 0; i < 16; i += 2) {
    int d0 = min(degU[i], MAXDEG), d1 = min(degU[i + 1], MAXDEG);   // uniform
    int l0 = max(d0 - 1, 0), l1 = max(d1 - 1, 0);
    unsigned v0[16], v1[16];
#pragma unroll
    for (int j = 0; j < 16; j++) {
      int s0 = (d0 > 0) ? __builtin_amdgcn_readlane(slot[i], min(j, l0)) : 0;
      v0[j] = xb[(size_t)s0 * 64 + lane];        // SGPR base + lane offset
    }
#pragma unroll
    for (int j = 0; j < 16; j++) {
      int s1 = (d1 > 0) ? __builtin_amdgcn_readlane(slot[i + 1], min(j, l1)) : 0;
      v1[j] = xb[(size_t)s1 * 64 + lane];
    }
    float a0 = 0.f, a1 = 0.f, b0 = 0.f, b1 = 0.f;
#pragma unroll
    for (int j = 0; j < 16; j++) {
      unsigned u0 = (j < d0) ? v0[j] : 0u;
      unsigned u1 = (j < d1) ? v1[j] : 0u;
      a0 += bflo(u0); a1 += bfhi(u0);
      b0 += bflo(u1); b1 += bfhi(u1);
    }
    // tails (deg > 16) — wave-uniform branches, serial batches
    for (int p = 16; p < d0; p += 16) {
      unsigned w[16];
#pragma unroll
      for (int j = 0; j < 16; j++) {
        int s = __builtin_amdgcn_readlane(slot[i], min(p + j, l0));
        w[j] = xb[(size_t)s * 64 + lane];
      }
#pragma unroll
      for (int j = 0; j < 16; j++) {
        unsigned u = (p + j < d0) ? w[j] : 0u;
        a0 += bflo(u); a1 += bfhi(u);
      }
    }
    for (int p = 16; p < d1; p += 16) {
      unsigned w[16];
#pragma unroll
      for (int j = 0; j < 16; j++) {
        int s = __builtin_amdgcn_readlane(slot[i + 1], min(p + j, l1));
        w[j] = xb[(size_t)s * 64 + lane];
      }
#pragma unroll
      for (int j = 0; j < 16; j++) {
        unsigned u = (p + j < d1) ? w[j] : 0u;
        b0 += bflo(u); b1 += bfhi(u);
      }
    }
    float inv0 = 1.f / (float)max(degU[i], 1);
    float inv1 = 1.f / (float)max(degU[i + 1], 1);
    unsigned pk0 = ((unsigned)f2bf(a1 * inv0) << 16) | f2bf(a0 * inv0);
    unsigned pk1 = ((unsigned)f2bf(b1 * inv1) << 16) | f2bf(b0 * inv1);
    ((unsigned*)&sA[wv * 16 + i][0])[lane]       = pk0;     // agg: k in [0,128)
    ((unsigned*)&sA[wv * 16 + i][128])[lane]     = xr[i];   // x:   k in [128,256)
    ((unsigned*)&sA[wv * 16 + i + 1][0])[lane]   = pk1;
    ((unsigned*)&sA[wv * 16 + i + 1][128])[lane] = xr[i + 1];
  }

  // ---- MFMA: A from my LDS rows, B from k-major WT in global (L2-hot) ----
  const int m = lane & 15;
  const int q = lane >> 4;

  f32x4 acc[M / 16];
#pragma unroll
  for (int c = 0; c < M / 16; c++) acc[c] = {0.f, 0.f, 0.f, 0.f};

#pragma unroll
  for (int ks = 0; ks < 8; ks++) {
    short8 a = *(const short8*)&sA[wv * 16 + m][ks * 32 + q * 8];   // A[m][q*8+j]
#pragma unroll
    for (int c = 0; c < M / 16; c++) {
      // B[k=q*8+j][n=c*16+m] = WT[n][k], contiguous 16B in k
      short8 b = *(const short8*)(WT + (size_t)(c * 16 + m) * 256 + ks * 32 + q * 8);
      acc[c] = __builtin_amdgcn_mfma_f32_16x16x32_bf16(a, b, acc[c], 0, 0, 0);
    }
  }

  // ---- epilogue: restage C through my (dead) sA rows -> full-line stores ----
#pragma unroll
  for (int c = 0; c < M / 16; c++) {
    int col = c * 16 + m;
    float bc = bias[col];
#pragma unroll
    for (int r = 0; r < 4; r++) {
      int lr = wv * 16 + q * 4 + r;               // D[row=q*4+r][col=m]
      float v = acc[c][r] + bc;
      if (RELU) v = fmaxf(v, 0.f);
      if constexpr (sizeof(OutT) == 2) sA[lr][col] = f2bf(v);
      else ((float*)&sA[lr][0])[col] = v;
    }
  }
#pragma unroll
  for (int it = 0; it < 4; it++) {
    int idx = it * 64 + lane;                     // 16 rows x 16 chunks of 16B
    int rr = idx >> 4, cc = idx & 15;
    int node = node0 + wv * 16 + rr;
    if (node < NN) {
      uint4 v = *(const uint4*)((const char*)&sA[wv * 16 + rr][0] + cc * 16);
      *(uint4*)((char*)(out + (size_t)node * M) + cc * 16) = v;
    }
  }
}

extern "C" void kernel_launch(void* const* d_in, const int* in_sizes, int n_in,
                              void* d_out, int out_size, void* d_ws, size_t ws_size,
                              hipStream_t stream) {
  const float* x   = (const float*)d_in[0];
  const int*   ei  = (const int*)d_in[1];
  const float* W1l = (const float*)d_in[2];
  const float* b1  = (const float*)d_in[3];
  const float* W1r = (const float*)d_in[4];
  const float* W2l = (const float*)d_in[5];
  const float* b2  = (const float*)d_in[6];
  const float* W2r = (const float*)d_in[7];
  float* out = (float*)d_out;

  // ws: cnt 0.5MB | buck 25.6MB | xbf 12.8MB | h 12.8MB | WT1 | WT2
  char* ws = (char*)d_ws;
  int* cnt  = (int*)ws;                                   ws += (512 << 10);
  int* buck = (int*)ws;                                   ws += (size_t)NN * MAXDEG * 4;
  unsigned* xbf = (unsigned*)ws;                          ws += (size_t)NN * 64 * 4;
  unsigned* hb = (unsigned*)ws;                           ws += (size_t)NN * 64 * 4;
  unsigned short* WT1 = (unsigned short*)ws;              ws += 128 * 256 * 2;
  unsigned short* WT2 = (unsigned short*)ws;              ws += 64 * 256 * 2;

  const int* src = ei;        // edge_index[0]
  const int* dst = ei + NE;   // edge_index[1]

  hipMemsetAsync(cnt, 0, (size_t)NN * 4, stream);
  build_buckets<<<NSLICE * (NE / CHUNK), 256, 0, stream>>>(src, dst, cnt, buck);
  to_bf16<<<(NN * 32 + 255) / 256, 256, 0, stream>>>(x, xbf);
  transpose_w<<<192, 256, 0, stream>>>(W1l, W1r, W2l, W2r, WT1, WT2);

  // layer 1: h = relu([mean|x] @ [W1l;W1r] + b1), bf16
  sage_fused<128, true, unsigned short><<<(NN + 63) / 64, 256, 0, stream>>>(
      xbf, cnt, buck, WT1, b1, (unsigned short*)hb);

  // layer 2: out = [mean|h] @ [W2l;W2r] + b2, f32
  sage_fused<64, false, float><<<(NN + 63) / 64, 256, 0, stream>>>(
      hb, cnt, buck, WT2, b2, out);
}

// Round 11
// 384.030 us; speedup vs baseline: 1.3840x; 1.3840x over previous
//
#include <hip/hip_runtime.h>
#include <stdint.h>

#define NN 100000      // nodes
#define NE 1600000     // edges
#define MAXDEG 64      // Poisson(16): P(deg>64) ~ 1e-19, safe cap
#define NSLICE 8       // XCD count; slice = blockIdx & 7 (perf heuristic only)
#define SLICE_SZ 12500 // nodes per slice
#define CHUNK 6400     // edges per block; NE/CHUNK = 250 chunks per slice

typedef __attribute__((ext_vector_type(8))) short short8;
typedef __attribute__((ext_vector_type(4))) float f32x4;
typedef __attribute__((ext_vector_type(4))) int i32x4;

__device__ __forceinline__ float bflo(unsigned v) { return __uint_as_float(v << 16); }
__device__ __forceinline__ float bfhi(unsigned v) { return __uint_as_float(v & 0xffff0000u); }
__device__ __forceinline__ unsigned short f2bf(float f) {   // round-to-nearest-even
  unsigned u = __float_as_uint(f);
  u += 0x7fff + ((u >> 16) & 1);
  return (unsigned short)(u >> 16);
}

// ---- XCD-sliced bucket build; NT edge reads keep the stream out of L2 ----
__global__ __launch_bounds__(256) void build_buckets(const int* __restrict__ src,
                                                     const int* __restrict__ dst,
                                                     int* __restrict__ cnt,
                                                     int* __restrict__ buck) {
  const int slice = blockIdx.x & (NSLICE - 1);
  const int chunk = blockIdx.x >> 3;
  const int c0 = chunk * CHUNK;
  const int lo = slice * SLICE_SZ, hi = lo + SLICE_SZ;
  for (int e = c0 + (int)threadIdx.x * 4; e < c0 + CHUNK; e += 1024) {
    i32x4 d = __builtin_nontemporal_load((const i32x4*)(dst + e));
    i32x4 s = __builtin_nontemporal_load((const i32x4*)(src + e));
    if (d[0] >= lo && d[0] < hi) { int p = atomicAdd(&cnt[d[0]], 1); if (p < MAXDEG) buck[d[0] * MAXDEG + p] = s[0]; }
    if (d[1] >= lo && d[1] < hi) { int p = atomicAdd(&cnt[d[1]], 1); if (p < MAXDEG) buck[d[1] * MAXDEG + p] = s[1]; }
    if (d[2] >= lo && d[2] < hi) { int p = atomicAdd(&cnt[d[2]], 1); if (p < MAXDEG) buck[d[2] * MAXDEG + p] = s[2]; }
    if (d[3] >= lo && d[3] < hi) { int p = atomicAdd(&cnt[d[3]], 1); if (p < MAXDEG) buck[d[3] * MAXDEG + p] = s[3]; }
  }
}

// ---- f32 -> packed bf16x2 (float4 per thread) ----
__global__ __launch_bounds__(256) void to_bf16(const float* __restrict__ x,
                                               unsigned* __restrict__ xb) {
  int i = blockIdx.x * 256 + threadIdx.x;     // over NN*32
  if (i >= NN * 32) return;
  float4 v = ((const float4*)x)[i];
  uint2 o;
  o.x = ((unsigned)f2bf(v.y) << 16) | f2bf(v.x);
  o.y = ((unsigned)f2bf(v.w) << 16) | f2bf(v.z);
  ((uint2*)xb)[i] = o;
}

// ---- one-time W transpose -> k-major bf16: WT[m][k], k = [Wl rows | Wr rows] ----
__global__ __launch_bounds__(256) void transpose_w(const float* __restrict__ W1l,
                                                   const float* __restrict__ W1r,
                                                   const float* __restrict__ W2l,
                                                   const float* __restrict__ W2r,
                                                   unsigned short* __restrict__ WT1,
                                                   unsigned short* __restrict__ WT2) {
  int t = blockIdx.x * 256 + threadIdx.x;
  if (t < 128 * 256) {
    int m = t >> 8, k = t & 255;
    float v = (k < 128) ? W1l[k * 128 + m] : W1r[(k - 128) * 128 + m];
    WT1[t] = f2bf(v);
  } else {
    int i = t - 128 * 256;
    if (i < 64 * 256) {
      int m = i >> 8, k = i & 255;
      float v = (k < 128) ? W2l[k * 64 + m] : W2r[(k - 128) * 64 + m];
      WT2[i] = f2bf(v);
    }
  }
}

// ---- FUSED layer: gather-mean into wave-private LDS rows, then MFMA.
// Barrier-free (wave wv owns rows [wv*16,wv*16+16)). Gather = round-9 shfl
// pattern (bpermute, known-good) but rows processed in PAIRS: both 16-load
// head batches issued back-to-back -> 32 loads in flight.
template <int M, bool RELU, typename OutT>
__global__ __launch_bounds__(256) void sage_fused(const unsigned* __restrict__ xb,
                                                  const int* __restrict__ cnt,
                                                  const int* __restrict__ buck,
                                                  const unsigned short* __restrict__ WT,
                                                  const float* __restrict__ bias,
                                                  OutT* __restrict__ out) {
  constexpr int LDA = 264;                       // +8 bf16 pad; 528B pitch
  __shared__ unsigned short sA[64][LDA];

  const int t = threadIdx.x;
  const int lane = t & 63;
  const int wv = t >> 6;
  const int node0 = blockIdx.x * 64;
  const int nb = node0 + wv * 16;                // this wave's 16 nodes

  // ---- prefetch: 16 bucket rows + 16 x rows + 16 degrees (independent) ----
  int slot[16]; unsigned xr[16]; int deg[16];
#pragma unroll
  for (int i = 0; i < 16; i++) {
    int node = nb + i;
    if (node < NN) {                             // wave-uniform branch
      slot[i] = buck[(size_t)node * MAXDEG + lane];
      xr[i]   = xb[(size_t)node * 64 + lane];
      deg[i]  = cnt[node];
    } else { slot[i] = 0; xr[i] = 0u; deg[i] = 0; }
  }

  // ---- gather-mean, rows in pairs: 32 head loads in flight ----
#pragma unroll
  for (int i = 0; i < 16; i += 2) {
    int dc0 = min(deg[i], MAXDEG), dc1 = min(deg[i + 1], MAXDEG);
    int l0 = max(dc0 - 1, 0), l1 = max(dc1 - 1, 0);
    unsigned v0[16], v1[16];
#pragma unroll
    for (int j = 0; j < 16; j++) {
      int s = __shfl(slot[i], min(j, l0), 64);
      v0[j] = xb[(size_t)s * 64 + lane];         // 256B/row coalesced
    }
#pragma unroll
    for (int j = 0; j < 16; j++) {
      int s = __shfl(slot[i + 1], min(j, l1), 64);
      v1[j] = xb[(size_t)s * 64 + lane];
    }
    float a0 = 0.f, a1 = 0.f, b0 = 0.f, b1 = 0.f;
#pragma unroll
    for (int j = 0; j < 16; j++) {
      unsigned u0 = (j < dc0) ? v0[j] : 0u;      // v_cndmask
      unsigned u1 = (j < dc1) ? v1[j] : 0u;
      a0 += bflo(u0); a1 += bfhi(u0);
      b0 += bflo(u1); b1 += bfhi(u1);
    }
    // tails (deg > 16) — wave-uniform, round-9 pattern
    for (int p = 16; p < dc0; p += 16) {
      unsigned w[16];
#pragma unroll
      for (int j = 0; j < 16; j++) {
        int s = __shfl(slot[i], min(p + j, l0), 64);
        w[j] = xb[(size_t)s * 64 + lane];
      }
#pragma unroll
      for (int j = 0; j < 16; j++) {
        unsigned u = (p + j < dc0) ? w[j] : 0u;
        a0 += bflo(u); a1 += bfhi(u);
      }
    }
    for (int p = 16; p < dc1; p += 16) {
      unsigned w[16];
#pragma unroll
      for (int j = 0; j < 16; j++) {
        int s = __shfl(slot[i + 1], min(p + j, l1), 64);
        w[j] = xb[(size_t)s * 64 + lane];
      }
#pragma unroll
      for (int j = 0; j < 16; j++) {
        unsigned u = (p + j < dc1) ? w[j] : 0u;
        b0 += bflo(u); b1 += bfhi(u);
      }
    }
    float inv0 = 1.f / (float)max(deg[i], 1);
    float inv1 = 1.f / (float)max(deg[i + 1], 1);
    unsigned pk0 = ((unsigned)f2bf(a1 * inv0) << 16) | f2bf(a0 * inv0);
    unsigned pk1 = ((unsigned)f2bf(b1 * inv1) << 16) | f2bf(b0 * inv1);
    ((unsigned*)&sA[wv * 16 + i][0])[lane]       = pk0;     // agg: k in [0,128)
    ((unsigned*)&sA[wv * 16 + i][128])[lane]     = xr[i];   // x:   k in [128,256)
    ((unsigned*)&sA[wv * 16 + i + 1][0])[lane]   = pk1;
    ((unsigned*)&sA[wv * 16 + i + 1][128])[lane] = xr[i + 1];
  }

  // ---- MFMA: A from my LDS rows, B from k-major WT in global (L2-hot) ----
  const int m = lane & 15;
  const int q = lane >> 4;

  f32x4 acc[M / 16];
#pragma unroll
  for (int c = 0; c < M / 16; c++) acc[c] = {0.f, 0.f, 0.f, 0.f};

#pragma unroll
  for (int ks = 0; ks < 8; ks++) {
    short8 a = *(const short8*)&sA[wv * 16 + m][ks * 32 + q * 8];   // A[m][q*8+j]
#pragma unroll
    for (int c = 0; c < M / 16; c++) {
      // B[k=q*8+j][n=c*16+m] = WT[n][k], contiguous 16B in k
      short8 b = *(const short8*)(WT + (size_t)(c * 16 + m) * 256 + ks * 32 + q * 8);
      acc[c] = __builtin_amdgcn_mfma_f32_16x16x32_bf16(a, b, acc[c], 0, 0, 0);
    }
  }

  // ---- epilogue: restage C through my (dead) sA rows -> full-line stores ----
#pragma unroll
  for (int c = 0; c < M / 16; c++) {
    int col = c * 16 + m;
    float bc = bias[col];
#pragma unroll
    for (int r = 0; r < 4; r++) {
      int lr = wv * 16 + q * 4 + r;               // D[row=q*4+r][col=m]
      float v = acc[c][r] + bc;
      if (RELU) v = fmaxf(v, 0.f);
      if constexpr (sizeof(OutT) == 2) sA[lr][col] = f2bf(v);
      else ((float*)&sA[lr][0])[col] = v;
    }
  }
#pragma unroll
  for (int it = 0; it < 4; it++) {
    int idx = it * 64 + lane;                     // 16 rows x 16 chunks of 16B
    int rr = idx >> 4, cc = idx & 15;
    int node = node0 + wv * 16 + rr;
    if (node < NN) {
      uint4 v = *(const uint4*)((const char*)&sA[wv * 16 + rr][0] + cc * 16);
      *(uint4*)((char*)(out + (size_t)node * M) + cc * 16) = v;
    }
  }
}

extern "C" void kernel_launch(void* const* d_in, const int* in_sizes, int n_in,
                              void* d_out, int out_size, void* d_ws, size_t ws_size,
                              hipStream_t stream) {
  const float* x   = (const float*)d_in[0];
  const int*   ei  = (const int*)d_in[1];
  const float* W1l = (const float*)d_in[2];
  const float* b1  = (const float*)d_in[3];
  const float* W1r = (const float*)d_in[4];
  const float* W2l = (const float*)d_in[5];
  const float* b2  = (const float*)d_in[6];
  const float* W2r = (const float*)d_in[7];
  float* out = (float*)d_out;

  // ws: cnt 0.5MB | buck 25.6MB | xbf 12.8MB | h 12.8MB | WT1 | WT2
  char* ws = (char*)d_ws;
  int* cnt  = (int*)ws;                                   ws += (512 << 10);
  int* buck = (int*)ws;                                   ws += (size_t)NN * MAXDEG * 4;
  unsigned* xbf = (unsigned*)ws;                          ws += (size_t)NN * 64 * 4;
  unsigned* hb = (unsigned*)ws;                           ws += (size_t)NN * 64 * 4;
  unsigned short* WT1 = (unsigned short*)ws;              ws += 128 * 256 * 2;
  unsigned short* WT2 = (unsigned short*)ws;              ws += 64 * 256 * 2;

  const int* src = ei;        // edge_index[0]
  const int* dst = ei + NE;   // edge_index[1]

  hipMemsetAsync(cnt, 0, (size_t)NN * 4, stream);
  build_buckets<<<NSLICE * (NE / CHUNK), 256, 0, stream>>>(src, dst, cnt, buck);
  to_bf16<<<(NN * 32 + 255) / 256, 256, 0, stream>>>(x, xbf);
  transpose_w<<<192, 256, 0, stream>>>(W1l, W1r, W2l, W2r, WT1, WT2);

  // layer 1: h = relu([mean|x] @ [W1l;W1r] + b1), bf16
  sage_fused<128, true, unsigned short><<<(NN + 63) / 64, 256, 0, stream>>>(
      xbf, cnt, buck, WT1, b1, (unsigned short*)hb);

  // layer 2: out = [mean|h] @ [W2l;W2r] + b2, f32
  sage_fused<64, false, float><<<(NN + 63) / 64, 256, 0, stream>>>(
      hb, cnt, buck, WT2, b2, out);
}